// Round 8
// baseline (723.971 us; speedup 1.0000x reference)
//
#include <hip/hip_runtime.h>

typedef __attribute__((ext_vector_type(8))) short bf16x8;
typedef __attribute__((ext_vector_type(4))) float f32x4;

static __device__ __forceinline__ short f2bf(float f) {
  union { float f; unsigned u; } v; v.f = f;
  unsigned r = v.u + 0x7fffu + ((v.u >> 16) & 1u);
  return (short)(r >> 16);
}
static __device__ __forceinline__ float bf2f(short s) {
  union { unsigned u; float f; } v; v.u = ((unsigned)(unsigned short)s) << 16;
  return v.f;
}

#define GLOBAL_AS(p) ((const __attribute__((address_space(1))) void*)(p))
#define LDS_AS(p)    ((__attribute__((address_space(3))) void*)(p))

// ---------------------------------------------------------------------------
// Batched prep: z<12 -> weight transpose+bf16 (512-row K-chunks);
// z==12 -> x0 fp32->bf16 grid-stride; z==13 -> zero deg/cursor/stats.
struct WD { const float* W; short* Wt; int ldt; int koff; int Nn; };
struct PrepArgs {
  WD d[12];
  const float* x0; short* xb0; int n8;
  int* deg; int* cursor; int ndeg; float* stats; int nstats;
};

__global__ void prep_kernel(PrepArgs P) {
  int z = blockIdx.z;
  if (z < 12) {
    __shared__ float tile[32][33];
    const WD dd = P.d[z];
    int kb = blockIdx.x * 32, nb = blockIdx.y * 32;
    if (nb >= dd.Nn) return;
    int tx = threadIdx.x & 31, ty = threadIdx.x >> 5;
#pragma unroll
    for (int j = 0; j < 4; ++j) {
      int k = kb + ty + 8 * j;
      tile[ty + 8 * j][tx] = dd.W[(size_t)k * dd.Nn + nb + tx];
    }
    __syncthreads();
#pragma unroll
    for (int j = 0; j < 4; ++j) {
      int n = nb + ty + 8 * j;
      dd.Wt[(size_t)n * dd.ldt + dd.koff + kb + tx] = f2bf(tile[tx][ty + 8 * j]);
    }
  } else if (z == 12) {
    int base = (blockIdx.y * 16 + blockIdx.x) * 256 + threadIdx.x;  // 65536 threads
    for (int i = base; i < P.n8; i += 65536) {
      float4 a = ((const float4*)P.x0)[i * 2];
      float4 b = ((const float4*)P.x0)[i * 2 + 1];
      short4 o1; o1.x = f2bf(a.x); o1.y = f2bf(a.y); o1.z = f2bf(a.z); o1.w = f2bf(a.w);
      short4 o2; o2.x = f2bf(b.x); o2.y = f2bf(b.y); o2.z = f2bf(b.z); o2.w = f2bf(b.w);
      ((short4*)P.xb0)[i * 2] = o1;
      ((short4*)P.xb0)[i * 2 + 1] = o2;
    }
  } else {
    int base = (blockIdx.y * 16 + blockIdx.x) * 256 + threadIdx.x;
    for (int i = base; i < P.ndeg; i += 65536) { P.deg[i] = 0; P.cursor[i] = 0; }
    for (int i = base; i < P.nstats; i += 65536) P.stats[i] = 0.f;
  }
}

// ---------------------------------------------------------------------------
// CSR build, all 3 layers.
struct L3s { const int* ei[3]; int E[3]; int dbase[3]; int ebase[3]; };

__global__ void deg_all_kernel(L3s L, int* __restrict__ deg) {
  int g = blockIdx.x * 256 + threadIdx.x;
  int l = 0, e = g;
  while (l < 3 && e >= L.E[l]) { e -= L.E[l]; ++l; }
  if (l >= 3) return;
  int d = L.ei[l][L.E[l] + e];
  atomicAdd(&deg[L.dbase[l] + d], 1);
}

__global__ void scan_all_kernel(L3s Ln, const int* __restrict__ deg, int* __restrict__ offs) {
  __shared__ int sums[257];
  int l = blockIdx.x;
  int n = Ln.E[l];
  const int* dg = deg + Ln.dbase[l];
  int* of = offs + Ln.dbase[l];
  int t = threadIdx.x;
  int per = (n + 255) / 256;
  int b = t * per, e = min(b + per, n);
  int s = 0;
  for (int i = b; i < e; ++i) s += dg[i];
  sums[t] = s;
  __syncthreads();
  if (t == 0) {
    int acc = 0;
    for (int i = 0; i < 256; ++i) { int v = sums[i]; sums[i] = acc; acc += v; }
    sums[256] = acc;
  }
  __syncthreads();
  int acc = sums[t];
  for (int i = b; i < e; ++i) { of[i] = acc; acc += dg[i]; }
  if (t == 255) of[n] = sums[256];
}

__global__ void fill_all_kernel(L3s L, const int* __restrict__ offs,
                                int* __restrict__ cursor, int* __restrict__ csr) {
  int g = blockIdx.x * 256 + threadIdx.x;
  int l = 0, e = g;
  while (l < 3 && e >= L.E[l]) { e -= L.E[l]; ++l; }
  if (l >= 3) return;
  int d = L.ei[l][L.E[l] + e];
  int p = atomicAdd(&cursor[L.dbase[l] + d], 1);
  csr[L.ebase[l] + offs[L.dbase[l] + d] + p] = L.ei[l][e];
}

// ---------------------------------------------------------------------------
// Gather aggregation, wave-per-node, 4-deep unroll. Mean half only.
__global__ void aggregate_kernel(const short* __restrict__ xb, const int* __restrict__ csr,
                                 const int* __restrict__ offs, short* __restrict__ A,
                                 int n_dst) {
  int node = blockIdx.x * 4 + (threadIdx.x >> 6);
  if (node >= n_dst) return;
  int lane = threadIdx.x & 63;
  const short* xp = xb + lane * 8;
  int s0 = offs[node], s1 = offs[node + 1];
  float a[8];
#pragma unroll
  for (int j = 0; j < 8; ++j) a[j] = 0.f;
  int e = s0;
  for (; e + 3 < s1; e += 4) {
    bf16x8 v0 = *(const bf16x8*)(xp + (size_t)csr[e] * 512);
    bf16x8 v1 = *(const bf16x8*)(xp + (size_t)csr[e + 1] * 512);
    bf16x8 v2 = *(const bf16x8*)(xp + (size_t)csr[e + 2] * 512);
    bf16x8 v3 = *(const bf16x8*)(xp + (size_t)csr[e + 3] * 512);
#pragma unroll
    for (int j = 0; j < 8; ++j) a[j] += (bf2f(v0[j]) + bf2f(v1[j])) + (bf2f(v2[j]) + bf2f(v3[j]));
  }
  for (; e < s1; ++e) {
    bf16x8 v0 = *(const bf16x8*)(xp + (size_t)csr[e] * 512);
#pragma unroll
    for (int j = 0; j < 8; ++j) a[j] += bf2f(v0[j]);
  }
  float inv = (s1 > s0) ? 1.0f / (float)(s1 - s0) : 0.0f;
  bf16x8 o;
#pragma unroll
  for (int j = 0; j < 8; ++j) o[j] = f2bf(a[j] * inv);
  *(bf16x8*)(A + (size_t)node * 512 + lane * 8) = o;
}

// ---------------------------------------------------------------------------
// Unified SAGE GEMM, templated M-tile: rows/block = 32*MI (MI=4 -> 128, MI=8 -> 256).
// Cols/block = 128. BK=64, XOR-swizzled LDS, XCD-grouped 1-D grid.
// A split: k<512 from Am (mean), k>=512 from Ax (x_dst rows). bn<gnMain: main
// path (B=Bt, C=hC/fC, fused stats); bn>=gnMain: res path (K 512..1024, B=Rt,
// C=rbuf bf16).
template <int MI>
__global__ __launch_bounds__(256, 2)
void sage_gemm_kernel(const short* __restrict__ Am, const short* __restrict__ Ax,
                      const short* __restrict__ Bt, int ldb,
                      short* __restrict__ hC, float* __restrict__ fC, int ldc,
                      int M, int K, const float* __restrict__ bias,
                      float* __restrict__ stats,
                      const short* __restrict__ Rt, short* __restrict__ rbuf,
                      int gm, int gnMain, int gnTot) {
  __shared__ short lds[2048 * MI + 8192];
  short* As = lds;                 // 32*MI rows x 64 k
  short* Bs = lds + 2048 * MI;     // 128 rows x 64 k
  const int id = blockIdx.x;
  const int g = id >> 3;
  const int bn = g % gnTot;
  const int bm = (g / gnTot) * 8 + (id & 7);
  if (bm >= gm) return;
  const bool resp = bn >= gnMain;
  const int tid = threadIdx.x;
  const int wid = tid >> 6;
  const int lane = tid & 63;
  const int lm = lane & 15;
  const int quad = lane >> 4;
  const int wr = wid >> 1, wc = wid & 1;
  const int srow = lane >> 3;
  const int kswz = (((lane & 7) ^ srow) << 3);
  const int ROWS = 32 * MI;

  f32x4 acc[MI][4];
#pragma unroll
  for (int i = 0; i < MI; ++i)
#pragma unroll
    for (int j = 0; j < 4; ++j) acc[i][j] = (f32x4)0.f;

  const int k0beg = resp ? 512 : 0;
  const int k0end = resp ? 1024 : K;
  for (int k0 = k0beg; k0 < k0end; k0 += 64) {
    const short* Aptr;
    int kloc;
    if (k0 < 512 && !resp) { Aptr = Am; kloc = k0; }
    else { Aptr = Ax; kloc = k0 - 512; }
#pragma unroll
    for (int j = 0; j < MI; ++j) {            // A: 4*MI chunks of 8 rows
      int ch = wid * MI + j;
      int arow = bm * ROWS + ch * 8 + srow;
      arow = arow < M ? arow : M - 1;
      const short* ga = Aptr + (size_t)arow * 512 + kloc + kswz;
      __builtin_amdgcn_global_load_lds(GLOBAL_AS(ga), LDS_AS(As + ch * 512), 16, 0, 0);
    }
#pragma unroll
    for (int j = 0; j < 4; ++j) {             // B: 16 chunks of 8 rows
      int ch = wid * 4 + j;
      const short* gb;
      if (resp) {
        int brow = (bn - gnMain) * 128 + ch * 8 + srow;
        gb = Rt + (size_t)brow * 512 + (k0 - 512) + kswz;
      } else {
        int brow = bn * 128 + ch * 8 + srow;
        gb = Bt + (size_t)brow * ldb + k0 + kswz;
      }
      __builtin_amdgcn_global_load_lds(GLOBAL_AS(gb), LDS_AS(Bs + ch * 512), 16, 0, 0);
    }
    __syncthreads();
#pragma unroll
    for (int ks = 0; ks < 2; ++ks) {
      bf16x8 af[MI], bfr[4];
      int xo = ((ks * 4 + quad) ^ (lm & 7)) * 8;
#pragma unroll
      for (int mi = 0; mi < MI; ++mi)
        af[mi] = *(const bf16x8*)(As + (wr * 16 * MI + mi * 16 + lm) * 64 + xo);
#pragma unroll
      for (int ni = 0; ni < 4; ++ni)
        bfr[ni] = *(const bf16x8*)(Bs + (wc * 64 + ni * 16 + lm) * 64 + xo);
#pragma unroll
      for (int mi = 0; mi < MI; ++mi)
#pragma unroll
        for (int ni = 0; ni < 4; ++ni)
          acc[mi][ni] = __builtin_amdgcn_mfma_f32_16x16x32_bf16(af[mi], bfr[ni], acc[mi][ni], 0, 0, 0);
    }
    __syncthreads();
  }

#pragma unroll
  for (int mi = 0; mi < MI; ++mi) {
#pragma unroll
    for (int ni = 0; ni < 4; ++ni) {
      int lcol = wc * 64 + ni * 16 + lm;
      int gcol = (resp ? (bn - gnMain) : bn) * 128 + lcol;
      float bv = (!resp && bias) ? bias[gcol] : 0.f;
#pragma unroll
      for (int r2 = 0; r2 < 4; ++r2) {
        int grow = bm * ROWS + wr * 16 * MI + mi * 16 + quad * 4 + r2;
        if (grow < M) {
          float val = acc[mi][ni][r2] + bv;
          if (resp)    rbuf[(size_t)grow * ldc + gcol] = f2bf(val);
          else if (hC) hC[(size_t)grow * ldc + gcol] = f2bf(val);
          else         fC[(size_t)grow * ldc + gcol] = val;
        }
      }
    }
  }

  if (stats && !resp) {
    float* s1 = (float*)lds;
    float* s2 = s1 + 128;
    if (tid < 128) { s1[tid] = 0.f; s2[tid] = 0.f; }
    __syncthreads();
#pragma unroll
    for (int ni = 0; ni < 4; ++ni) {
      int cloc = wc * 64 + ni * 16 + lm;
      float p1 = 0.f, p2 = 0.f;
#pragma unroll
      for (int mi = 0; mi < MI; ++mi)
#pragma unroll
        for (int r2 = 0; r2 < 4; ++r2) {
          int grow = bm * ROWS + wr * 16 * MI + mi * 16 + quad * 4 + r2;
          if (grow < M) {
            float v = acc[mi][ni][r2];
            p1 += v; p2 += v * v;
          }
        }
      atomicAdd(&s1[cloc], p1);
      atomicAdd(&s2[cloc], p2);
    }
    __syncthreads();
    if (tid < 128) {
      int gcol = bn * 128 + tid;
      atomicAdd(&stats[gcol], s1[tid]);
      atomicAdd(&stats[512 + gcol], s2[tid]);
    }
  }
}

// ---------------------------------------------------------------------------
// Head GEMM-1: A staged from 4 bf16 x-buffers (concat along K). 128x128.
__global__ __launch_bounds__(256, 2)
void gemm4_kernel(const short* __restrict__ p0, const short* __restrict__ p1,
                  const short* __restrict__ p2, const short* __restrict__ p3,
                  const short* __restrict__ Bt, int ldb,
                  short* __restrict__ Cb, int ldc,
                  int M, int N, const float* __restrict__ bias, int gm, int gn) {
  const int K = 2048;
  __shared__ short lds[16384];
  short* As = lds;
  short* Bs = lds + 8192;
  const int id = blockIdx.x;
  const int g = id >> 3;
  const int bn = g % gn;
  const int bm = (g / gn) * 8 + (id & 7);
  if (bm >= gm) return;
  const int tid = threadIdx.x;
  const int wid = tid >> 6;
  const int lane = tid & 63;
  const int lm = lane & 15;
  const int quad = lane >> 4;
  const int wr = wid >> 1, wc = wid & 1;
  const int srow = lane >> 3;
  const int kswz = (((lane & 7) ^ srow) << 3);

  f32x4 acc[4][4];
#pragma unroll
  for (int i = 0; i < 4; ++i)
#pragma unroll
    for (int j = 0; j < 4; ++j) acc[i][j] = (f32x4)0.f;

  for (int k0 = 0; k0 < K; k0 += 64) {
    const short* Asrc = (k0 < 512) ? p0 : (k0 < 1024) ? p1 : (k0 < 1536) ? p2 : p3;
    int kloc = k0 & 511;
#pragma unroll
    for (int j = 0; j < 4; ++j) {
      int ch = wid * 4 + j;
      int arow = bm * 128 + ch * 8 + srow;
      arow = arow < M ? arow : M - 1;
      const short* ga = Asrc + (size_t)arow * 512 + kloc + kswz;
      __builtin_amdgcn_global_load_lds(GLOBAL_AS(ga), LDS_AS(As + ch * 512), 16, 0, 0);
      int brow = bn * 128 + ch * 8 + srow;
      const short* gb = Bt + (size_t)brow * ldb + k0 + kswz;
      __builtin_amdgcn_global_load_lds(GLOBAL_AS(gb), LDS_AS(Bs + ch * 512), 16, 0, 0);
    }
    __syncthreads();
#pragma unroll
    for (int ks = 0; ks < 2; ++ks) {
      bf16x8 af[4], bfr[4];
      int xo = ((ks * 4 + quad) ^ (lm & 7)) * 8;
#pragma unroll
      for (int mi = 0; mi < 4; ++mi)
        af[mi] = *(const bf16x8*)(As + (wr * 64 + mi * 16 + lm) * 64 + xo);
#pragma unroll
      for (int ni = 0; ni < 4; ++ni)
        bfr[ni] = *(const bf16x8*)(Bs + (wc * 64 + ni * 16 + lm) * 64 + xo);
#pragma unroll
      for (int mi = 0; mi < 4; ++mi)
#pragma unroll
        for (int ni = 0; ni < 4; ++ni)
          acc[mi][ni] = __builtin_amdgcn_mfma_f32_16x16x32_bf16(af[mi], bfr[ni], acc[mi][ni], 0, 0, 0);
    }
    __syncthreads();
  }

#pragma unroll
  for (int mi = 0; mi < 4; ++mi) {
#pragma unroll
    for (int ni = 0; ni < 4; ++ni) {
      int gcol = bn * 128 + wc * 64 + ni * 16 + lm;
      float bv = bias[gcol];
#pragma unroll
      for (int r2 = 0; r2 < 4; ++r2) {
        int grow = bm * 128 + wr * 64 + mi * 16 + quad * 4 + r2;
        if (grow < M) Cb[(size_t)grow * ldc + gcol] = f2bf(acc[mi][ni][r2] + bv);
      }
    }
  }
}

// ---------------------------------------------------------------------------
// x_out(bf16) = leaky(BN(h_bf16; stats)) + (rbuf_bf16 + res_b | xdst_bf16).
__global__ void apply_kernel(const short* __restrict__ h, const float* __restrict__ stats,
                             const float* __restrict__ g, const float* __restrict__ b,
                             const short* __restrict__ r, const float* __restrict__ res_b,
                             const short* __restrict__ xdst, short* __restrict__ outp,
                             int n, float inv_n) {
  int i = blockIdx.x;
  int c = threadIdx.x * 4;
  short4 hb = *(const short4*)(h + (size_t)i * 512 + c);
  float4 s1 = *(const float4*)(stats + c);
  float4 s2 = *(const float4*)(stats + 512 + c);
  float4 gv = *(const float4*)(g + c);
  float4 bv = *(const float4*)(b + c);
  float mux = s1.x * inv_n, muy = s1.y * inv_n, muz = s1.z * inv_n, muw = s1.w * inv_n;
  float rsx = rsqrtf(s2.x * inv_n - mux * mux + 1e-5f);
  float rsy = rsqrtf(s2.y * inv_n - muy * muy + 1e-5f);
  float rsz = rsqrtf(s2.z * inv_n - muz * muz + 1e-5f);
  float rsw = rsqrtf(s2.w * inv_n - muw * muw + 1e-5f);
  float4 o;
  o.x = (bf2f(hb.x) - mux) * rsx * gv.x + bv.x;
  o.y = (bf2f(hb.y) - muy) * rsy * gv.y + bv.y;
  o.z = (bf2f(hb.z) - muz) * rsz * gv.z + bv.z;
  o.w = (bf2f(hb.w) - muw) * rsw * gv.w + bv.w;
  o.x = o.x >= 0.f ? o.x : 0.01f * o.x;
  o.y = o.y >= 0.f ? o.y : 0.01f * o.y;
  o.z = o.z >= 0.f ? o.z : 0.01f * o.z;
  o.w = o.w >= 0.f ? o.w : 0.01f * o.w;
  if (r) {
    short4 rv = *(const short4*)(r + (size_t)i * 512 + c);
    float4 rb = *(const float4*)(res_b + c);
    o.x += bf2f(rv.x) + rb.x; o.y += bf2f(rv.y) + rb.y;
    o.z += bf2f(rv.z) + rb.z; o.w += bf2f(rv.w) + rb.w;
  } else {
    short4 xv = *(const short4*)(xdst + (size_t)i * 512 + c);
    o.x += bf2f(xv.x); o.y += bf2f(xv.y); o.z += bf2f(xv.z); o.w += bf2f(xv.w);
  }
  short4 ov;
  ov.x = f2bf(o.x); ov.y = f2bf(o.y); ov.z = f2bf(o.z); ov.w = f2bf(o.w);
  *(short4*)(outp + (size_t)i * 512 + c) = ov;
}

// ---------------------------------------------------------------------------
__global__ void lsm_kernel(const float* __restrict__ z, float* __restrict__ outp) {
  __shared__ float redm[4], reds[4];
  int row = blockIdx.x, t = threadIdx.x;
  float v = z[(size_t)row * 256 + t];
  float m = v;
#pragma unroll
  for (int o = 32; o >= 1; o >>= 1) m = fmaxf(m, __shfl_down(m, o, 64));
  if ((t & 63) == 0) redm[t >> 6] = m;
  __syncthreads();
  m = fmaxf(fmaxf(redm[0], redm[1]), fmaxf(redm[2], redm[3]));
  float e = __expf(v - m);
  float s = e;
#pragma unroll
  for (int o = 32; o >= 1; o >>= 1) s += __shfl_down(s, o, 64);
  if ((t & 63) == 0) reds[t >> 6] = s;
  __syncthreads();
  s = reds[0] + reds[1] + reds[2] + reds[3];
  outp[(size_t)row * 256 + t] = v - m - __logf(s);
}

// ---------------------------------------------------------------------------
extern "C" void kernel_launch(void* const* d_in, const int* in_sizes, int n_in,
                              void* d_out, int out_size, void* d_ws, size_t ws_size,
                              hipStream_t stream) {
  const float* x0 = (const float*)d_in[0];
  const int* eis[3] = {(const int*)d_in[1], (const int*)d_in[2], (const int*)d_in[3]};
  const float* Wl[3] = {(const float*)d_in[4], (const float*)d_in[8], (const float*)d_in[12]};
  const float* Wr[3] = {(const float*)d_in[5], (const float*)d_in[9], (const float*)d_in[13]};
  const float* gg[3] = {(const float*)d_in[6], (const float*)d_in[10], (const float*)d_in[14]};
  const float* bb[3] = {(const float*)d_in[7], (const float*)d_in[11], (const float*)d_in[15]};
  const float* res_W = (const float*)d_in[16];
  const float* res_b = (const float*)d_in[17];
  const float* mlp_W1 = (const float*)d_in[18];
  const float* mlp_b1 = (const float*)d_in[19];
  const float* mlp_W2 = (const float*)d_in[20];
  const float* mlp_b2 = (const float*)d_in[21];
  float* out = (float*)d_out;

  const int Ns[4] = {60000, 30000, 15000, 8000};
  int Es[3];
  for (int l = 0; l < 3; ++l) Es[l] = in_sizes[1 + l] / 2;
  int Etot = Es[0] + Es[1] + Es[2];

  char* ws = (char*)d_ws;
  size_t off = 0;
  auto alloc = [&](size_t bytes) { size_t r = off; off += (bytes + 255) & ~(size_t)255; return r; };
  short* Bt[3];
  Bt[0] = (short*)(ws + alloc(512 * 1024 * 2));
  Bt[1] = (short*)(ws + alloc(512 * 1024 * 2));
  Bt[2] = (short*)(ws + alloc(512 * 1024 * 2));
  short* Rt = (short*)(ws + alloc(512 * 512 * 2));
  short* W1t = (short*)(ws + alloc(512 * 2048 * 2));
  short* W2t = (short*)(ws + alloc(256 * 512 * 2));
  const int dbase[3] = {0, 30001, 45002};
  const int ndeg = 53003;
  int ebase[3] = {0, Es[0], Es[0] + Es[1]};
  int* deg3 = (int*)(ws + alloc((size_t)ndeg * 4));
  int* offs3 = (int*)(ws + alloc((size_t)ndeg * 4));
  int* cursor3 = (int*)(ws + alloc((size_t)ndeg * 4));
  int* csr3 = (int*)(ws + alloc((size_t)Etot * 4));
  float* stats3 = (float*)(ws + alloc(3 * 1024 * 4));
  short* xb0 = (short*)(ws + alloc((size_t)60000 * 512 * 2));
  short* x1b = (short*)(ws + alloc((size_t)30000 * 512 * 2));
  short* x2b = (short*)(ws + alloc((size_t)15000 * 512 * 2));
  short* x3b = (short*)(ws + alloc((size_t)8000 * 512 * 2));
  short* Abuf = (short*)(ws + alloc((size_t)30000 * 512 * 2));
  short* h = (short*)(ws + alloc((size_t)30000 * 512 * 2));
  size_t scr_off = alloc((size_t)30000 * 512 * 2);
  short* rbuf = (short*)(ws + scr_off);
  short* z1b = (short*)(ws + scr_off);
  float* z2 = (float*)(ws + alloc((size_t)8000 * 256 * 4));

  // ---- prep: weights + x0 conversion + zeroing, one dispatch ----
  PrepArgs P;
  P.d[0] = {Wl[0], Bt[0], 1024, 0, 512};
  P.d[1] = {Wr[0], Bt[0], 1024, 512, 512};
  P.d[2] = {Wl[1], Bt[1], 1024, 0, 512};
  P.d[3] = {Wr[1], Bt[1], 1024, 512, 512};
  P.d[4] = {Wl[2], Bt[2], 1024, 0, 512};
  P.d[5] = {Wr[2], Bt[2], 1024, 512, 512};
  P.d[6] = {res_W, Rt, 512, 0, 512};
  P.d[7] = {mlp_W1 + 0 * 512 * 512, W1t, 2048, 0, 512};
  P.d[8] = {mlp_W1 + 1 * 512 * 512, W1t, 2048, 512, 512};
  P.d[9] = {mlp_W1 + 2 * 512 * 512, W1t, 2048, 1024, 512};
  P.d[10] = {mlp_W1 + 3 * 512 * 512, W1t, 2048, 1536, 512};
  P.d[11] = {mlp_W2, W2t, 512, 0, 256};
  P.x0 = x0; P.xb0 = xb0; P.n8 = 60000 * 512 / 8;
  P.deg = deg3; P.cursor = cursor3; P.ndeg = ndeg;
  P.stats = stats3; P.nstats = 3 * 1024;
  prep_kernel<<<dim3(16, 16, 14), 256, 0, stream>>>(P);

  // ---- CSR build ----
  L3s L;
  for (int l = 0; l < 3; ++l) {
    L.ei[l] = eis[l]; L.E[l] = Es[l]; L.dbase[l] = dbase[l]; L.ebase[l] = ebase[l];
  }
  deg_all_kernel<<<dim3((Etot + 255) / 256), 256, 0, stream>>>(L, deg3);
  L3s Ln = L;
  Ln.E[0] = Ns[1]; Ln.E[1] = Ns[2]; Ln.E[2] = Ns[3];
  scan_all_kernel<<<dim3(3), 256, 0, stream>>>(Ln, deg3, offs3);
  fill_all_kernel<<<dim3((Etot + 255) / 256), 256, 0, stream>>>(L, offs3, cursor3, csr3);

  const short* xin[3] = {xb0, x1b, x2b};
  short* xout[3] = {x1b, x2b, x3b};

  auto gblocks = [](int gm, int gn) { return ((gm + 7) / 8) * 8 * gn; };

  for (int l = 0; l < 3; ++l) {
    int n_dst = Ns[l + 1];
    float* stats = stats3 + l * 1024;
    aggregate_kernel<<<dim3((n_dst + 3) / 4), 256, 0, stream>>>(
        xin[l], csr3 + ebase[l], offs3 + dbase[l], Abuf, n_dst);
    if (l < 2) {
      // 256-row tiles for the big-M layers
      int gm = (n_dst + 255) / 256;
      int gnTot = (l == 0) ? 8 : 4;
      sage_gemm_kernel<8><<<dim3(gblocks(gm, gnTot)), 256, 0, stream>>>(
          Abuf, xin[l], Bt[l], 1024, h, nullptr, 512, n_dst, 1024, nullptr, stats,
          Rt, rbuf, gm, 4, gnTot);
    } else {
      int gm = (n_dst + 127) / 128;
      sage_gemm_kernel<4><<<dim3(gblocks(gm, 4)), 256, 0, stream>>>(
          Abuf, xin[l], Bt[l], 1024, h, nullptr, 512, n_dst, 1024, nullptr, stats,
          nullptr, nullptr, gm, 4, 4);
    }
    apply_kernel<<<dim3(n_dst), 128, 0, stream>>>(h, stats, gg[l], bb[l],
                                                  l == 0 ? rbuf : nullptr, res_b,
                                                  xin[l], xout[l], n_dst, 1.0f / n_dst);
  }

  // ---- head ----
  {
    int gm = (8000 + 127) / 128;  // 63
    gemm4_kernel<<<dim3(gblocks(gm, 4)), 256, 0, stream>>>(
        xb0, x1b, x2b, x3b, W1t, 2048, z1b, 512, 8000, 512, mlp_b1, gm, 4);
    sage_gemm_kernel<4><<<dim3(gblocks(gm, 2)), 256, 0, stream>>>(
        z1b, nullptr, W2t, 512, nullptr, z2, 256, 8000, 512, mlp_b2, nullptr,
        nullptr, nullptr, gm, 2, 2);
  }
  lsm_kernel<<<dim3(8000), 256, 0, stream>>>(z2, out);
}

// Round 9
// 687.044 us; speedup vs baseline: 1.0537x; 1.0537x over previous
//
#include <hip/hip_runtime.h>

typedef __attribute__((ext_vector_type(8))) short bf16x8;
typedef __attribute__((ext_vector_type(4))) float f32x4;

static __device__ __forceinline__ short f2bf(float f) {
  union { float f; unsigned u; } v; v.f = f;
  unsigned r = v.u + 0x7fffu + ((v.u >> 16) & 1u);
  return (short)(r >> 16);
}
static __device__ __forceinline__ float bf2f(short s) {
  union { unsigned u; float f; } v; v.u = ((unsigned)(unsigned short)s) << 16;
  return v.f;
}

#define GLOBAL_AS(p) ((const __attribute__((address_space(1))) void*)(p))
#define LDS_AS(p)    ((__attribute__((address_space(3))) void*)(p))

// ---------------------------------------------------------------------------
// Batched prep: z<12 -> weight transpose+bf16 (512-row K-chunks);
// z==12 -> x0 fp32->bf16 grid-stride; z==13 -> zero deg/cursor/stats.
struct WD { const float* W; short* Wt; int ldt; int koff; int Nn; };
struct PrepArgs {
  WD d[12];
  const float* x0; short* xb0; int n8;
  int* deg; int* cursor; int ndeg; float* stats; int nstats;
};

__global__ void prep_kernel(PrepArgs P) {
  int z = blockIdx.z;
  if (z < 12) {
    __shared__ float tile[32][33];
    const WD dd = P.d[z];
    int kb = blockIdx.x * 32, nb = blockIdx.y * 32;
    if (nb >= dd.Nn) return;
    int tx = threadIdx.x & 31, ty = threadIdx.x >> 5;
#pragma unroll
    for (int j = 0; j < 4; ++j) {
      int k = kb + ty + 8 * j;
      tile[ty + 8 * j][tx] = dd.W[(size_t)k * dd.Nn + nb + tx];
    }
    __syncthreads();
#pragma unroll
    for (int j = 0; j < 4; ++j) {
      int n = nb + ty + 8 * j;
      dd.Wt[(size_t)n * dd.ldt + dd.koff + kb + tx] = f2bf(tile[tx][ty + 8 * j]);
    }
  } else if (z == 12) {
    int base = (blockIdx.y * 16 + blockIdx.x) * 256 + threadIdx.x;  // 65536 threads
    for (int i = base; i < P.n8; i += 65536) {
      float4 a = ((const float4*)P.x0)[i * 2];
      float4 b = ((const float4*)P.x0)[i * 2 + 1];
      short4 o1; o1.x = f2bf(a.x); o1.y = f2bf(a.y); o1.z = f2bf(a.z); o1.w = f2bf(a.w);
      short4 o2; o2.x = f2bf(b.x); o2.y = f2bf(b.y); o2.z = f2bf(b.z); o2.w = f2bf(b.w);
      ((short4*)P.xb0)[i * 2] = o1;
      ((short4*)P.xb0)[i * 2 + 1] = o2;
    }
  } else {
    int base = (blockIdx.y * 16 + blockIdx.x) * 256 + threadIdx.x;
    for (int i = base; i < P.ndeg; i += 65536) { P.deg[i] = 0; P.cursor[i] = 0; }
    for (int i = base; i < P.nstats; i += 65536) P.stats[i] = 0.f;
  }
}

// ---------------------------------------------------------------------------
// CSR build, all 3 layers.
struct L3s { const int* ei[3]; int E[3]; int dbase[3]; int ebase[3]; };

__global__ void deg_all_kernel(L3s L, int* __restrict__ deg) {
  int g = blockIdx.x * 256 + threadIdx.x;
  int l = 0, e = g;
  while (l < 3 && e >= L.E[l]) { e -= L.E[l]; ++l; }
  if (l >= 3) return;
  int d = L.ei[l][L.E[l] + e];
  atomicAdd(&deg[L.dbase[l] + d], 1);
}

__global__ void scan_all_kernel(L3s Ln, const int* __restrict__ deg, int* __restrict__ offs) {
  __shared__ int sums[257];
  int l = blockIdx.x;
  int n = Ln.E[l];
  const int* dg = deg + Ln.dbase[l];
  int* of = offs + Ln.dbase[l];
  int t = threadIdx.x;
  int per = (n + 255) / 256;
  int b = t * per, e = min(b + per, n);
  int s = 0;
  for (int i = b; i < e; ++i) s += dg[i];
  sums[t] = s;
  __syncthreads();
  if (t == 0) {
    int acc = 0;
    for (int i = 0; i < 256; ++i) { int v = sums[i]; sums[i] = acc; acc += v; }
    sums[256] = acc;
  }
  __syncthreads();
  int acc = sums[t];
  for (int i = b; i < e; ++i) { of[i] = acc; acc += dg[i]; }
  if (t == 255) of[n] = sums[256];
}

__global__ void fill_all_kernel(L3s L, const int* __restrict__ offs,
                                int* __restrict__ cursor, int* __restrict__ csr) {
  int g = blockIdx.x * 256 + threadIdx.x;
  int l = 0, e = g;
  while (l < 3 && e >= L.E[l]) { e -= L.E[l]; ++l; }
  if (l >= 3) return;
  int d = L.ei[l][L.E[l] + e];
  int p = atomicAdd(&cursor[L.dbase[l] + d], 1);
  csr[L.ebase[l] + offs[L.dbase[l] + d] + p] = L.ei[l][e];
}

// ---------------------------------------------------------------------------
// Gather aggregation, wave-per-node, 4-deep unroll. Mean half only.
__global__ void aggregate_kernel(const short* __restrict__ xb, const int* __restrict__ csr,
                                 const int* __restrict__ offs, short* __restrict__ A,
                                 int n_dst) {
  int node = blockIdx.x * 4 + (threadIdx.x >> 6);
  if (node >= n_dst) return;
  int lane = threadIdx.x & 63;
  const short* xp = xb + lane * 8;
  int s0 = offs[node], s1 = offs[node + 1];
  float a[8];
#pragma unroll
  for (int j = 0; j < 8; ++j) a[j] = 0.f;
  int e = s0;
  for (; e + 3 < s1; e += 4) {
    bf16x8 v0 = *(const bf16x8*)(xp + (size_t)csr[e] * 512);
    bf16x8 v1 = *(const bf16x8*)(xp + (size_t)csr[e + 1] * 512);
    bf16x8 v2 = *(const bf16x8*)(xp + (size_t)csr[e + 2] * 512);
    bf16x8 v3 = *(const bf16x8*)(xp + (size_t)csr[e + 3] * 512);
#pragma unroll
    for (int j = 0; j < 8; ++j) a[j] += (bf2f(v0[j]) + bf2f(v1[j])) + (bf2f(v2[j]) + bf2f(v3[j]));
  }
  for (; e < s1; ++e) {
    bf16x8 v0 = *(const bf16x8*)(xp + (size_t)csr[e] * 512);
#pragma unroll
    for (int j = 0; j < 8; ++j) a[j] += bf2f(v0[j]);
  }
  float inv = (s1 > s0) ? 1.0f / (float)(s1 - s0) : 0.0f;
  bf16x8 o;
#pragma unroll
  for (int j = 0; j < 8; ++j) o[j] = f2bf(a[j] * inv);
  *(bf16x8*)(A + (size_t)node * 512 + lane * 8) = o;
}

// ---------------------------------------------------------------------------
// SAGE GEMM, 128x128, BK=64, XOR-swizzled LDS, XCD-grouped 1-D grid.
// A split: k<512 from Am, k>=512 from Ax (both 512-wide rows).
// C -> hC (bf16) or fC (fp32); optional fused column stats.
__global__ __launch_bounds__(256, 3)
void sage_gemm_kernel(const short* __restrict__ Am, const short* __restrict__ Ax,
                      const short* __restrict__ Bt, int ldb,
                      short* __restrict__ hC, float* __restrict__ fC, int ldc,
                      int M, int K, const float* __restrict__ bias,
                      float* __restrict__ stats, int gm, int gn) {
  __shared__ short lds[16384];
  short* As = lds;
  short* Bs = lds + 8192;
  const int id = blockIdx.x;
  const int g = id >> 3;
  const int bn = g % gn;
  const int bm = (g / gn) * 8 + (id & 7);
  if (bm >= gm) return;
  const int tid = threadIdx.x;
  const int wid = tid >> 6;
  const int lane = tid & 63;
  const int lm = lane & 15;
  const int quad = lane >> 4;
  const int wr = wid >> 1, wc = wid & 1;
  const int srow = lane >> 3;
  const int kswz = (((lane & 7) ^ srow) << 3);

  f32x4 acc[4][4];
#pragma unroll
  for (int i = 0; i < 4; ++i)
#pragma unroll
    for (int j = 0; j < 4; ++j) acc[i][j] = (f32x4)0.f;

  for (int k0 = 0; k0 < K; k0 += 64) {
    const short* Aptr = (k0 < 512) ? Am : Ax;
    int kloc = k0 & 511;
#pragma unroll
    for (int j = 0; j < 4; ++j) {
      int ch = wid * 4 + j;
      int arow = bm * 128 + ch * 8 + srow;
      arow = arow < M ? arow : M - 1;
      const short* ga = Aptr + (size_t)arow * 512 + kloc + kswz;
      __builtin_amdgcn_global_load_lds(GLOBAL_AS(ga), LDS_AS(As + ch * 512), 16, 0, 0);
      int brow = bn * 128 + ch * 8 + srow;
      const short* gb = Bt + (size_t)brow * ldb + k0 + kswz;
      __builtin_amdgcn_global_load_lds(GLOBAL_AS(gb), LDS_AS(Bs + ch * 512), 16, 0, 0);
    }
    __syncthreads();
#pragma unroll
    for (int ks = 0; ks < 2; ++ks) {
      bf16x8 af[4], bfr[4];
      int xo = ((ks * 4 + quad) ^ (lm & 7)) * 8;
#pragma unroll
      for (int mi = 0; mi < 4; ++mi)
        af[mi] = *(const bf16x8*)(As + (wr * 64 + mi * 16 + lm) * 64 + xo);
#pragma unroll
      for (int ni = 0; ni < 4; ++ni)
        bfr[ni] = *(const bf16x8*)(Bs + (wc * 64 + ni * 16 + lm) * 64 + xo);
#pragma unroll
      for (int mi = 0; mi < 4; ++mi)
#pragma unroll
        for (int ni = 0; ni < 4; ++ni)
          acc[mi][ni] = __builtin_amdgcn_mfma_f32_16x16x32_bf16(af[mi], bfr[ni], acc[mi][ni], 0, 0, 0);
    }
    __syncthreads();
  }

#pragma unroll
  for (int mi = 0; mi < 4; ++mi) {
#pragma unroll
    for (int ni = 0; ni < 4; ++ni) {
      int gcol = bn * 128 + wc * 64 + ni * 16 + lm;
      float bv = bias ? bias[gcol] : 0.f;
#pragma unroll
      for (int r2 = 0; r2 < 4; ++r2) {
        int grow = bm * 128 + wr * 64 + mi * 16 + quad * 4 + r2;
        if (grow < M) {
          float val = acc[mi][ni][r2] + bv;
          if (hC) hC[(size_t)grow * ldc + gcol] = f2bf(val);
          else    fC[(size_t)grow * ldc + gcol] = val;
        }
      }
    }
  }

  if (stats) {
    float* s1 = (float*)lds;
    float* s2 = s1 + 128;
    if (tid < 128) { s1[tid] = 0.f; s2[tid] = 0.f; }
    __syncthreads();
#pragma unroll
    for (int ni = 0; ni < 4; ++ni) {
      int cloc = wc * 64 + ni * 16 + lm;
      float p1 = 0.f, p2 = 0.f;
#pragma unroll
      for (int mi = 0; mi < 4; ++mi)
#pragma unroll
        for (int r2 = 0; r2 < 4; ++r2) {
          int grow = bm * 128 + wr * 64 + mi * 16 + quad * 4 + r2;
          if (grow < M) {
            float v = acc[mi][ni][r2];
            p1 += v; p2 += v * v;
          }
        }
      atomicAdd(&s1[cloc], p1);
      atomicAdd(&s2[cloc], p2);
    }
    __syncthreads();
    if (tid < 128) {
      int gcol = bn * 128 + tid;
      atomicAdd(&stats[gcol], s1[tid]);
      atomicAdd(&stats[512 + gcol], s2[tid]);
    }
  }
}

// ---------------------------------------------------------------------------
// Head GEMM-1: A staged from 4 bf16 x-buffers (concat along K). 128x128.
__global__ __launch_bounds__(256, 3)
void gemm4_kernel(const short* __restrict__ p0, const short* __restrict__ p1,
                  const short* __restrict__ p2, const short* __restrict__ p3,
                  const short* __restrict__ Bt, int ldb,
                  short* __restrict__ Cb, int ldc,
                  int M, int N, const float* __restrict__ bias, int gm, int gn) {
  const int K = 2048;
  __shared__ short lds[16384];
  short* As = lds;
  short* Bs = lds + 8192;
  const int id = blockIdx.x;
  const int g = id >> 3;
  const int bn = g % gn;
  const int bm = (g / gn) * 8 + (id & 7);
  if (bm >= gm) return;
  const int tid = threadIdx.x;
  const int wid = tid >> 6;
  const int lane = tid & 63;
  const int lm = lane & 15;
  const int quad = lane >> 4;
  const int wr = wid >> 1, wc = wid & 1;
  const int srow = lane >> 3;
  const int kswz = (((lane & 7) ^ srow) << 3);

  f32x4 acc[4][4];
#pragma unroll
  for (int i = 0; i < 4; ++i)
#pragma unroll
    for (int j = 0; j < 4; ++j) acc[i][j] = (f32x4)0.f;

  for (int k0 = 0; k0 < K; k0 += 64) {
    const short* Asrc = (k0 < 512) ? p0 : (k0 < 1024) ? p1 : (k0 < 1536) ? p2 : p3;
    int kloc = k0 & 511;
#pragma unroll
    for (int j = 0; j < 4; ++j) {
      int ch = wid * 4 + j;
      int arow = bm * 128 + ch * 8 + srow;
      arow = arow < M ? arow : M - 1;
      const short* ga = Asrc + (size_t)arow * 512 + kloc + kswz;
      __builtin_amdgcn_global_load_lds(GLOBAL_AS(ga), LDS_AS(As + ch * 512), 16, 0, 0);
      int brow = bn * 128 + ch * 8 + srow;
      const short* gb = Bt + (size_t)brow * ldb + k0 + kswz;
      __builtin_amdgcn_global_load_lds(GLOBAL_AS(gb), LDS_AS(Bs + ch * 512), 16, 0, 0);
    }
    __syncthreads();
#pragma unroll
    for (int ks = 0; ks < 2; ++ks) {
      bf16x8 af[4], bfr[4];
      int xo = ((ks * 4 + quad) ^ (lm & 7)) * 8;
#pragma unroll
      for (int mi = 0; mi < 4; ++mi)
        af[mi] = *(const bf16x8*)(As + (wr * 64 + mi * 16 + lm) * 64 + xo);
#pragma unroll
      for (int ni = 0; ni < 4; ++ni)
        bfr[ni] = *(const bf16x8*)(Bs + (wc * 64 + ni * 16 + lm) * 64 + xo);
#pragma unroll
      for (int mi = 0; mi < 4; ++mi)
#pragma unroll
        for (int ni = 0; ni < 4; ++ni)
          acc[mi][ni] = __builtin_amdgcn_mfma_f32_16x16x32_bf16(af[mi], bfr[ni], acc[mi][ni], 0, 0, 0);
    }
    __syncthreads();
  }

#pragma unroll
  for (int mi = 0; mi < 4; ++mi) {
#pragma unroll
    for (int ni = 0; ni < 4; ++ni) {
      int gcol = bn * 128 + wc * 64 + ni * 16 + lm;
      float bv = bias[gcol];
#pragma unroll
      for (int r2 = 0; r2 < 4; ++r2) {
        int grow = bm * 128 + wr * 64 + mi * 16 + quad * 4 + r2;
        if (grow < M) Cb[(size_t)grow * ldc + gcol] = f2bf(acc[mi][ni][r2] + bv);
      }
    }
  }
}

// ---------------------------------------------------------------------------
// x_out(bf16) = leaky(BN(h_bf16; stats)) + (rbuf_bf16 + res_b | xdst_bf16).
__global__ void apply_kernel(const short* __restrict__ h, const float* __restrict__ stats,
                             const float* __restrict__ g, const float* __restrict__ b,
                             const short* __restrict__ r, const float* __restrict__ res_b,
                             const short* __restrict__ xdst, short* __restrict__ outp,
                             int n, float inv_n) {
  int i = blockIdx.x;
  int c = threadIdx.x * 4;
  short4 hb = *(const short4*)(h + (size_t)i * 512 + c);
  float4 s1 = *(const float4*)(stats + c);
  float4 s2 = *(const float4*)(stats + 512 + c);
  float4 gv = *(const float4*)(g + c);
  float4 bv = *(const float4*)(b + c);
  float mux = s1.x * inv_n, muy = s1.y * inv_n, muz = s1.z * inv_n, muw = s1.w * inv_n;
  float rsx = rsqrtf(s2.x * inv_n - mux * mux + 1e-5f);
  float rsy = rsqrtf(s2.y * inv_n - muy * muy + 1e-5f);
  float rsz = rsqrtf(s2.z * inv_n - muz * muz + 1e-5f);
  float rsw = rsqrtf(s2.w * inv_n - muw * muw + 1e-5f);
  float4 o;
  o.x = (bf2f(hb.x) - mux) * rsx * gv.x + bv.x;
  o.y = (bf2f(hb.y) - muy) * rsy * gv.y + bv.y;
  o.z = (bf2f(hb.z) - muz) * rsz * gv.z + bv.z;
  o.w = (bf2f(hb.w) - muw) * rsw * gv.w + bv.w;
  o.x = o.x >= 0.f ? o.x : 0.01f * o.x;
  o.y = o.y >= 0.f ? o.y : 0.01f * o.y;
  o.z = o.z >= 0.f ? o.z : 0.01f * o.z;
  o.w = o.w >= 0.f ? o.w : 0.01f * o.w;
  if (r) {
    short4 rv = *(const short4*)(r + (size_t)i * 512 + c);
    float4 rb = *(const float4*)(res_b + c);
    o.x += bf2f(rv.x) + rb.x; o.y += bf2f(rv.y) + rb.y;
    o.z += bf2f(rv.z) + rb.z; o.w += bf2f(rv.w) + rb.w;
  } else {
    short4 xv = *(const short4*)(xdst + (size_t)i * 512 + c);
    o.x += bf2f(xv.x); o.y += bf2f(xv.y); o.z += bf2f(xv.z); o.w += bf2f(xv.w);
  }
  short4 ov;
  ov.x = f2bf(o.x); ov.y = f2bf(o.y); ov.z = f2bf(o.z); ov.w = f2bf(o.w);
  *(short4*)(outp + (size_t)i * 512 + c) = ov;
}

// ---------------------------------------------------------------------------
__global__ void lsm_kernel(const float* __restrict__ z, float* __restrict__ outp) {
  __shared__ float redm[4], reds[4];
  int row = blockIdx.x, t = threadIdx.x;
  float v = z[(size_t)row * 256 + t];
  float m = v;
#pragma unroll
  for (int o = 32; o >= 1; o >>= 1) m = fmaxf(m, __shfl_down(m, o, 64));
  if ((t & 63) == 0) redm[t >> 6] = m;
  __syncthreads();
  m = fmaxf(fmaxf(redm[0], redm[1]), fmaxf(redm[2], redm[3]));
  float e = __expf(v - m);
  float s = e;
#pragma unroll
  for (int o = 32; o >= 1; o >>= 1) s += __shfl_down(s, o, 64);
  if ((t & 63) == 0) reds[t >> 6] = s;
  __syncthreads();
  s = reds[0] + reds[1] + reds[2] + reds[3];
  outp[(size_t)row * 256 + t] = v - m - __logf(s);
}

// ---------------------------------------------------------------------------
extern "C" void kernel_launch(void* const* d_in, const int* in_sizes, int n_in,
                              void* d_out, int out_size, void* d_ws, size_t ws_size,
                              hipStream_t stream) {
  const float* x0 = (const float*)d_in[0];
  const int* eis[3] = {(const int*)d_in[1], (const int*)d_in[2], (const int*)d_in[3]};
  const float* Wl[3] = {(const float*)d_in[4], (const float*)d_in[8], (const float*)d_in[12]};
  const float* Wr[3] = {(const float*)d_in[5], (const float*)d_in[9], (const float*)d_in[13]};
  const float* gg[3] = {(const float*)d_in[6], (const float*)d_in[10], (const float*)d_in[14]};
  const float* bb[3] = {(const float*)d_in[7], (const float*)d_in[11], (const float*)d_in[15]};
  const float* res_W = (const float*)d_in[16];
  const float* res_b = (const float*)d_in[17];
  const float* mlp_W1 = (const float*)d_in[18];
  const float* mlp_b1 = (const float*)d_in[19];
  const float* mlp_W2 = (const float*)d_in[20];
  const float* mlp_b2 = (const float*)d_in[21];
  float* out = (float*)d_out;

  const int Ns[4] = {60000, 30000, 15000, 8000};
  int Es[3];
  for (int l = 0; l < 3; ++l) Es[l] = in_sizes[1 + l] / 2;
  int Etot = Es[0] + Es[1] + Es[2];

  char* ws = (char*)d_ws;
  size_t off = 0;
  auto alloc = [&](size_t bytes) { size_t r = off; off += (bytes + 255) & ~(size_t)255; return r; };
  short* Bt[3];
  Bt[0] = (short*)(ws + alloc(512 * 1024 * 2));
  Bt[1] = (short*)(ws + alloc(512 * 1024 * 2));
  Bt[2] = (short*)(ws + alloc(512 * 1024 * 2));
  short* Rt = (short*)(ws + alloc(512 * 512 * 2));
  short* W1t = (short*)(ws + alloc(512 * 2048 * 2));
  short* W2t = (short*)(ws + alloc(256 * 512 * 2));
  const int dbase[3] = {0, 30001, 45002};
  const int ndeg = 53003;
  int ebase[3] = {0, Es[0], Es[0] + Es[1]};
  int* deg3 = (int*)(ws + alloc((size_t)ndeg * 4));
  int* offs3 = (int*)(ws + alloc((size_t)ndeg * 4));
  int* cursor3 = (int*)(ws + alloc((size_t)ndeg * 4));
  int* csr3 = (int*)(ws + alloc((size_t)Etot * 4));
  float* stats3 = (float*)(ws + alloc(3 * 1024 * 4));
  short* xb0 = (short*)(ws + alloc((size_t)60000 * 512 * 2));
  short* x1b = (short*)(ws + alloc((size_t)30000 * 512 * 2));
  short* x2b = (short*)(ws + alloc((size_t)15000 * 512 * 2));
  short* x3b = (short*)(ws + alloc((size_t)8000 * 512 * 2));
  short* Abuf = (short*)(ws + alloc((size_t)30000 * 512 * 2));
  short* h = (short*)(ws + alloc((size_t)30000 * 512 * 2));
  size_t scr_off = alloc((size_t)30000 * 512 * 2);
  short* rbuf = (short*)(ws + scr_off);
  short* z1b = (short*)(ws + scr_off);
  float* z2 = (float*)(ws + alloc((size_t)8000 * 256 * 4));

  // ---- prep: weights + x0 conversion + zeroing, one dispatch ----
  PrepArgs P;
  P.d[0] = {Wl[0], Bt[0], 1024, 0, 512};
  P.d[1] = {Wr[0], Bt[0], 1024, 512, 512};
  P.d[2] = {Wl[1], Bt[1], 1024, 0, 512};
  P.d[3] = {Wr[1], Bt[1], 1024, 512, 512};
  P.d[4] = {Wl[2], Bt[2], 1024, 0, 512};
  P.d[5] = {Wr[2], Bt[2], 1024, 512, 512};
  P.d[6] = {res_W, Rt, 512, 0, 512};
  P.d[7] = {mlp_W1 + 0 * 512 * 512, W1t, 2048, 0, 512};
  P.d[8] = {mlp_W1 + 1 * 512 * 512, W1t, 2048, 512, 512};
  P.d[9] = {mlp_W1 + 2 * 512 * 512, W1t, 2048, 1024, 512};
  P.d[10] = {mlp_W1 + 3 * 512 * 512, W1t, 2048, 1536, 512};
  P.d[11] = {mlp_W2, W2t, 512, 0, 256};
  P.x0 = x0; P.xb0 = xb0; P.n8 = 60000 * 512 / 8;
  P.deg = deg3; P.cursor = cursor3; P.ndeg = ndeg;
  P.stats = stats3; P.nstats = 3 * 1024;
  prep_kernel<<<dim3(16, 16, 14), 256, 0, stream>>>(P);

  // ---- CSR build ----
  L3s L;
  for (int l = 0; l < 3; ++l) {
    L.ei[l] = eis[l]; L.E[l] = Es[l]; L.dbase[l] = dbase[l]; L.ebase[l] = ebase[l];
  }
  deg_all_kernel<<<dim3((Etot + 255) / 256), 256, 0, stream>>>(L, deg3);
  L3s Ln = L;
  Ln.E[0] = Ns[1]; Ln.E[1] = Ns[2]; Ln.E[2] = Ns[3];
  scan_all_kernel<<<dim3(3), 256, 0, stream>>>(Ln, deg3, offs3);
  fill_all_kernel<<<dim3((Etot + 255) / 256), 256, 0, stream>>>(L, offs3, cursor3, csr3);

  const short* xin[3] = {xb0, x1b, x2b};
  short* xout[3] = {x1b, x2b, x3b};

  auto gblocks = [](int gm, int gn) { return ((gm + 7) / 8) * 8 * gn; };

  for (int l = 0; l < 3; ++l) {
    int n_dst = Ns[l + 1];
    float* stats = stats3 + l * 1024;
    aggregate_kernel<<<dim3((n_dst + 3) / 4), 256, 0, stream>>>(
        xin[l], csr3 + ebase[l], offs3 + dbase[l], Abuf, n_dst);
    int gm = (n_dst + 127) / 128;
    sage_gemm_kernel<<<dim3(gblocks(gm, 4)), 256, 0, stream>>>(
        Abuf, xin[l], Bt[l], 1024, h, nullptr, 512, n_dst, 1024, nullptr, stats, gm, 4);
    if (l == 0)
      sage_gemm_kernel<<<dim3(gblocks(gm, 4)), 256, 0, stream>>>(
          xin[l], nullptr, Rt, 512, rbuf, nullptr, 512, n_dst, 512, nullptr, nullptr, gm, 4);
    apply_kernel<<<dim3(n_dst), 128, 0, stream>>>(h, stats, gg[l], bb[l],
                                                  l == 0 ? rbuf : nullptr, res_b,
                                                  xin[l], xout[l], n_dst, 1.0f / n_dst);
  }

  // ---- head ----
  {
    int gm = (8000 + 127) / 128;  // 63
    gemm4_kernel<<<dim3(gblocks(gm, 4)), 256, 0, stream>>>(
        xb0, x1b, x2b, x3b, W1t, 2048, z1b, 512, 8000, 512, mlp_b1, gm, 4);
    sage_gemm_kernel<<<dim3(gblocks(gm, 2)), 256, 0, stream>>>(
        z1b, nullptr, W2t, 512, nullptr, z2, 256, 8000, 512, mlp_b2, nullptr, gm, 2);
  }
  lsm_kernel<<<dim3(8000), 256, 0, stream>>>(z2, out);
}